// Round 2
// baseline (78.959 us; speedup 1.0000x reference)
//
#include <hip/hip_runtime.h>

// MQuantileLoss: B=4096 rows, N=8192 cols fp32.
// Per row m in {estimate, target}: CDF quantiles at q={.25,.5,.75} with
// piecewise-linear interp (x = 1..N, i==0 interpolates from (0,0)); output
// mean |q_est - q_tgt|.
//
// Layout: thread t loads float4 at element seg*1024 + t*4  -> each wave
// load instruction covers a contiguous 1 KiB span (fully coalesced).
// Group gi = seg*256 + t owns elements [4*gi, 4*gi+4). Group bases are
// built with an exact shared-memory block scan so ownership is decided
// purely from the shared array (exactly-one-owner under rounding).

constexpr int BLOCK = 256;
constexpr int NCOL  = 8192;
constexpr int NSEG  = NCOL / (4 * BLOCK);   // 8 segments of 1024 elements
constexpr int NGRP  = NCOL / 4;             // 2048 groups of 4

__global__ __launch_bounds__(BLOCK) void mquantile_fused(
    const float* __restrict__ pe, const float* __restrict__ pt,
    float* __restrict__ out, float inv_total)
{
    __shared__ float b[NGRP + 1];     // group sums, then exclusive group bases
    __shared__ float wsum[4];
    __shared__ float qsc[2][3];
    const int row  = blockIdx.x;
    const int tid  = threadIdx.x;
    const int lane = tid & 63, wave = tid >> 6;
    const float qs[3] = {0.25f, 0.5f, 0.75f};

    for (int m = 0; m < 2; ++m) {
        const float* rp = (m == 0 ? pe : pt) + (size_t)row * NCOL;

        // 1. Coalesced load + group sums into LDS (bank: gi%32 = tid%32, 2-way free).
        #pragma unroll
        for (int s = 0; s < NSEG; ++s) {
            const float4 v = *reinterpret_cast<const float4*>(rp + s * 1024 + tid * 4);
            b[s * BLOCK + tid] = v.x + v.y + v.z + v.w;
        }
        __syncthreads();                               // (A) group sums visible

        // 2. Transposed scan: thread t scans groups [8t, 8t+8).
        float g[8];
        float lsum = 0.f;
        #pragma unroll
        for (int j = 0; j < 8; ++j) { g[j] = b[tid * 8 + j]; lsum += g[j]; }

        float x = lsum;                                // wave inclusive scan
        #pragma unroll
        for (int off = 1; off < 64; off <<= 1) {
            const float y = __shfl_up(x, off, 64);
            if (lane >= off) x += y;
        }
        if (lane == 63) wsum[wave] = x;
        __syncthreads();                               // (B) g reads done, wsum visible

        float wbase = 0.f;
        #pragma unroll
        for (int w = 0; w < 4; ++w) if (w < wave) wbase += wsum[w];
        float excl = __shfl_up(x, 1, 64);
        if (lane == 0) excl = 0.f;
        float run = wbase + excl;                      // exclusive base of group 8t
        #pragma unroll
        for (int j = 0; j < 8; ++j) { b[tid * 8 + j] = run; run += g[j]; }
        if (tid == BLOCK - 1) b[NGRP] = run;           // total
        __syncthreads();                               // (C) bases visible

        // 3. Ownership + 4-element walk. Conditions use ONLY the shared b[]
        //    array, so for any q < b[NGRP] at least one group matches
        //    (b[0]==0 < q, crossing argument); duplicates write the same slot.
        float b0[NSEG], b1[NSEG];
        #pragma unroll
        for (int s = 0; s < NSEG; ++s) {
            b0[s] = b[s * BLOCK + tid];
            b1[s] = b[s * BLOCK + tid + 1];
        }
        const float total = b[NGRP];
        #pragma unroll
        for (int qi = 0; qi < 3; ++qi) {
            const float q = qs[qi];
            #pragma unroll
            for (int s = 0; s < NSEG; ++s) {
                const int gi = s * BLOCK + tid;
                const bool owner = (b0[s] < q && b1[s] >= q) ||
                                   (gi == NGRP - 1 && total < q);  // clip path
                if (owner) {
                    const float4 v = *reinterpret_cast<const float4*>(rp + s * 1024 + tid * 4);
                    const float vv[4] = {v.x, v.y, v.z, v.w};
                    float runw = b0[s], prev = b0[s], Yb = 0.f, Ya = 0.f;
                    int idx = -1;
                    #pragma unroll
                    for (int c = 0; c < 4; ++c) {
                        prev = runw; runw += vv[c];
                        if (idx < 0 && runw >= q) { idx = c; Yb = runw; Ya = prev; }
                    }
                    if (idx < 0) { idx = 3; Yb = runw; Ya = prev; }  // rounding fallback
                    // score = (i+1) + (q - cdf[i]) / (cdf[i] - cdf[i-1]); Ya==0 at i==0.
                    qsc[m][qi] = (float)(gi * 4 + idx + 1) + (q - Yb) / (Yb - Ya);
                }
            }
        }
        __syncthreads();                               // (D) qsc visible, b[] reusable
    }

    if (tid == 0) {
        const float s = fabsf(qsc[0][0] - qsc[1][0]) +
                        fabsf(qsc[0][1] - qsc[1][1]) +
                        fabsf(qsc[0][2] - qsc[1][2]);
        atomicAdd(out, s * inv_total);
    }
}

extern "C" void kernel_launch(void* const* d_in, const int* in_sizes, int n_in,
                              void* d_out, int out_size, void* d_ws, size_t ws_size,
                              hipStream_t stream) {
    const float* pe = (const float*)d_in[0];   // p_estimate
    const float* pt = (const float*)d_in[1];   // p_target
    const int B = in_sizes[0] / NCOL;
    hipMemsetAsync(d_out, 0, sizeof(float), stream);
    mquantile_fused<<<B, BLOCK, 0, stream>>>(pe, pt, (float*)d_out,
                                             1.0f / (3.0f * (float)B));
}